// Round 7
// baseline (171.898 us; speedup 1.0000x reference)
//
#include <hip/hip_runtime.h>

// Ordered bi-bi mechanism dydt. Species: [E, EA, EQ, EAB, A, B, P, Q].
//
// ONE THREAD PER ELEMENT, exchange-free (R5: removing the 8-shfl
// vmcnt->lgkmcnt chain was 60->43us). R7: PERSISTENT grid-stride with a
// 1-deep software pipeline — the untested structure combo. R6 (one-shot,
// all loads issued in a burst at t=0) shows a drain-tail signature
// (OccupancyPercent 38%, read delivery pinned ~3.0 TB/s while the harness's
// own write-only fill hits 6.36 TB/s). Persistent waves keep issuing the
// next element's loads while computing the current one => constant
// concurrency start-to-finish instead of burst-then-drain.
//
// Stores: regular cached (R6: nt stores at 32B lane stride caused +31%
// write amplification; cached stores merge in L2, WRITE_SIZE exact 62.5 MB).
// Loads: regular cached (R2 vs R6: FETCH identical with/without nt; give L3
// the best chance to re-install inputs for the next bench iteration).

typedef float v4f __attribute__((ext_vector_type(4)));

__device__ __forceinline__ void ode_elem(v4f ya, v4f yb, v4f f, v4f r,
                                         v4f& oa, v4f& ob) {
    float E  = ya.x, EA = ya.y, EQ = ya.z, EAB = ya.w;
    float A  = yb.x, Bc = yb.y, P  = yb.z, Q   = yb.w;

    float v0 = f.x * E   * A  - r.x * EA;
    float v1 = f.y * EA  * Bc - r.y * EAB;
    float v2 = f.z * EAB      - r.z * EQ * P;
    float v3 = f.w * EQ       - r.w * E  * Q;

    oa.x = v3 - v0;   // dE
    oa.y = v0 - v1;   // dEA
    oa.z = v2 - v3;   // dEQ
    oa.w = v1 - v2;   // dEAB
    ob.x = -v0;       // dA
    ob.y = -v1;       // dB
    ob.z =  v2;       // dP
    ob.w =  v3;       // dQ
}

__global__ __launch_bounds__(256, 8) void ode_kernel(
    const v4f* __restrict__ y4,
    const v4f* __restrict__ kf4,
    const v4f* __restrict__ kr4,
    v4f* __restrict__ out4,
    int B)    // number of elements
{
    const int T = gridDim.x * blockDim.x;   // grid stride in elements
    int e = blockIdx.x * blockDim.x + threadIdx.x;

    // ---- software pipeline prologue: load element e ----
    bool v = e < B;
    v4f ya, yb, f, r;
    if (v) {
        ya = y4[2 * e];
        yb = y4[2 * e + 1];
        f  = kf4[e];
        r  = kr4[e];
    }

    while (v) {
        // prefetch element e+T while computing/storing element e
        int  en = e + T;
        bool vn = en < B;
        v4f yan, ybn, fn, rn;
        if (vn) {
            yan = y4[2 * en];
            ybn = y4[2 * en + 1];
            fn  = kf4[en];
            rn  = kr4[en];
        }

        v4f oa, ob;
        ode_elem(ya, yb, f, r, oa, ob);
        out4[2 * e]     = oa;   // cached: L2 merges half-line pairs
        out4[2 * e + 1] = ob;

        e = en; v = vn;
        ya = yan; yb = ybn; f = fn; r = rn;
    }
}

extern "C" void kernel_launch(void* const* d_in, const int* in_sizes, int n_in,
                              void* d_out, int out_size, void* d_ws, size_t ws_size,
                              hipStream_t stream) {
    // inputs: [0]=t (1,), [1]=y (B,8), [2]=forward_rates (B,4), [3]=reverse_rates (B,4)
    const v4f* y4  = (const v4f*)d_in[1];
    const v4f* kf4 = (const v4f*)d_in[2];
    const v4f* kr4 = (const v4f*)d_in[3];
    v4f* out4 = (v4f*)d_out;
    int B = in_sizes[1] / 8;

    // Persistent grid: 8 blocks/CU x 256 CUs = 2048 blocks, 32 waves/CU
    // resident throughout (~4 grid-stride iterations per thread).
    int block = 256;
    int grid  = 2048;
    int maxg  = (B + block - 1) / block;
    if (grid > maxg) grid = maxg;
    ode_kernel<<<grid, block, 0, stream>>>(y4, kf4, kr4, out4, B);
}

// Round 8
// 171.608 us; speedup vs baseline: 1.0017x; 1.0017x over previous
//
#include <hip/hip_runtime.h>

// Ordered bi-bi mechanism dydt. Species: [E, EA, EQ, EAB, A, B, P, Q].
//
// R8: LDS-staged layout transform, one-shot burst grid (the winning shape).
// Diagnosis across R0-R7: 60us kernels = low per-thread in-flight bytes;
// 43us kernels = one-shot burst with >=128B/thread in flight. Remaining
// inefficiency of the 43us kernels: y-loads and out-stores are 16B accesses
// at 32B lane stride => every wave instruction requests 32 full cache lines
// but covers only half of each (sibling instruction re-requests the same
// lines) => ~1.67x minimum line-request rate. This version makes EVERY
// global access a fully-covered unit-stride float4:
//   - y tile loaded unit-stride into LDS, per-element gather from LDS
//   - output computed into LDS, stored unit-stride from LDS
//   - kf/kr already unit-stride, stay in registers
// Thread t gathers exactly the LDS slots it later overwrites (read set ==
// write set per thread), so no barrier is needed between gather and
// write-back: 2 barriers per tile total. DS pipe was 100% idle; the 4-way
// bank conflict on the strided gather (ds_read_b128 @ 32B stride) is benign.

typedef float v4f __attribute__((ext_vector_type(4)));

#define TPB 256

__device__ __forceinline__ void ode_elem(v4f ya, v4f yb, v4f f, v4f r,
                                         v4f& oa, v4f& ob) {
    float E  = ya.x, EA = ya.y, EQ = ya.z, EAB = ya.w;
    float A  = yb.x, Bc = yb.y, P  = yb.z, Q   = yb.w;

    float v0 = f.x * E   * A  - r.x * EA;
    float v1 = f.y * EA  * Bc - r.y * EAB;
    float v2 = f.z * EAB      - r.z * EQ * P;
    float v3 = f.w * EQ       - r.w * E  * Q;

    oa.x = v3 - v0;   // dE
    oa.y = v0 - v1;   // dEA
    oa.z = v2 - v3;   // dEQ
    oa.w = v1 - v2;   // dEAB
    ob.x = -v0;       // dA
    ob.y = -v1;       // dB
    ob.z =  v2;       // dP
    ob.w =  v3;       // dQ
}

__global__ __launch_bounds__(TPB) void ode_kernel(
    const v4f* __restrict__ y4,
    const v4f* __restrict__ kf4,
    const v4f* __restrict__ kr4,
    v4f* __restrict__ out4,
    int B)    // number of elements
{
    __shared__ v4f buf[2 * TPB];          // 8 KB tile buffer

    const int tid  = threadIdx.x;
    const int base = blockIdx.x * TPB;    // first element of this tile
    const int n2   = 2 * B;

    const int gy0 = 2 * base + tid;       // unit-stride float4 rows of y
    const int gy1 = gy0 + TPB;
    const int e   = base + tid;           // this thread's element

    // ---- fully-covered unit-stride global loads (burst) ----
    v4f a0 = {0.f, 0.f, 0.f, 0.f}, a1 = {0.f, 0.f, 0.f, 0.f};
    v4f f  = {0.f, 0.f, 0.f, 0.f}, r  = {0.f, 0.f, 0.f, 0.f};
    if (gy0 < n2) a0 = y4[gy0];
    if (gy1 < n2) a1 = y4[gy1];
    if (e < B) { f = kf4[e]; r = kr4[e]; }

    // stage y tile into LDS in load order
    buf[tid]       = a0;
    buf[tid + TPB] = a1;
    __syncthreads();

    // per-element gather (32B-stride ds_read_b128, 4-way conflict: benign)
    v4f ya = buf[2 * tid];
    v4f yb = buf[2 * tid + 1];

    v4f oa, ob;
    ode_elem(ya, yb, f, r, oa, ob);

    // write-back into the SAME slots this thread just read — no cross-thread
    // hazard (read set == write set per thread), so no barrier before this.
    buf[2 * tid]     = oa;
    buf[2 * tid + 1] = ob;
    __syncthreads();

    // ---- fully-covered unit-stride global stores ----
    if (gy0 < n2) out4[gy0] = buf[tid];
    if (gy1 < n2) out4[gy1] = buf[tid + TPB];
}

extern "C" void kernel_launch(void* const* d_in, const int* in_sizes, int n_in,
                              void* d_out, int out_size, void* d_ws, size_t ws_size,
                              hipStream_t stream) {
    // inputs: [0]=t (1,), [1]=y (B,8), [2]=forward_rates (B,4), [3]=reverse_rates (B,4)
    const v4f* y4  = (const v4f*)d_in[1];
    const v4f* kf4 = (const v4f*)d_in[2];
    const v4f* kr4 = (const v4f*)d_in[3];
    v4f* out4 = (v4f*)d_out;
    int B = in_sizes[1] / 8;

    int grid = (B + TPB - 1) / TPB;   // one 256-element tile per block
    ode_kernel<<<grid, TPB, 0, stream>>>(y4, kf4, kr4, out4, B);
}